// Round 7
// baseline (1827.345 us; speedup 1.0000x reference)
//
#include <hip/hip_runtime.h>

#define BB 32
#define DIM 4096
#define NH 32
#define NKV 8
#define HD 128
#define KVLEN 4096
#define QKVC 6144  // DIM + 2*NKV*HD
#define GQ 4
#define QKV_SPLITS 32
#define WO_SPLITS 32
#define ASPLIT 4   // KV splits for k_attn (1024 keys each)

typedef const __attribute__((address_space(1))) char gas_char;
typedef __attribute__((address_space(3))) char las_char;
#define GLL16(GP, LP) __builtin_amdgcn_global_load_lds((gas_char*)(GP), (las_char*)(LP), 16, 0, 0)

// ---------------- kernel A: xqkv partials = x @ wqkv (K-split, partials) -------
__global__ __launch_bounds__(256, 4) void k_qkv(const float* __restrict__ x,
                                                const float* __restrict__ w,
                                                float* __restrict__ part) {
    int j  = blockIdx.x * 256 + threadIdx.x;          // column 0..6143 (24 blocks)
    int d0 = blockIdx.y * (DIM / QKV_SPLITS);         // 128 rows per split
    float acc[BB];
#pragma unroll
    for (int b = 0; b < BB; ++b) acc[b] = 0.f;
    for (int dd = d0; dd < d0 + DIM / QKV_SPLITS; dd += 16) {
        float wr[16];   // 16-deep weight pipeline: 16x256B per wave in flight
#pragma unroll
        for (int k = 0; k < 16; ++k) wr[k] = w[(size_t)(dd + k) * QKVC + j];
#pragma unroll
        for (int b = 0; b < BB; ++b) {
            float4 xa = *(const float4*)&x[b * DIM + dd];      // wave-uniform
            float4 xb = *(const float4*)&x[b * DIM + dd + 4];
            float4 xc = *(const float4*)&x[b * DIM + dd + 8];
            float4 xd = *(const float4*)&x[b * DIM + dd + 12];
            float t = acc[b];
            t = fmaf(xa.x, wr[0],  t); t = fmaf(xa.y, wr[1],  t);
            t = fmaf(xa.z, wr[2],  t); t = fmaf(xa.w, wr[3],  t);
            t = fmaf(xb.x, wr[4],  t); t = fmaf(xb.y, wr[5],  t);
            t = fmaf(xb.z, wr[6],  t); t = fmaf(xb.w, wr[7],  t);
            t = fmaf(xc.x, wr[8],  t); t = fmaf(xc.y, wr[9],  t);
            t = fmaf(xc.z, wr[10], t); t = fmaf(xc.w, wr[11], t);
            t = fmaf(xd.x, wr[12], t); t = fmaf(xd.y, wr[13], t);
            t = fmaf(xd.z, wr[14], t); t = fmaf(xd.w, wr[15], t);
            acc[b] = t;
        }
    }
#pragma unroll
    for (int b = 0; b < BB; ++b)
        part[(size_t)blockIdx.y * (BB * QKVC) + (size_t)b * QKVC + j] = acc[b];
}

// ---------------- generic split reduction: dst = sum_p src[p] ------------------
__global__ __launch_bounds__(256) void k_red(const float* __restrict__ src,
                                             float* __restrict__ dst,
                                             int parts, int n4) {
    int i = blockIdx.x * 256 + threadIdx.x;
    if (i >= n4) return;
    const float4* s4 = (const float4*)src;
    float4 a = s4[i];
    for (int p = 1; p < parts; ++p) {
        float4 b = s4[(size_t)p * n4 + i];
        a.x += b.x; a.y += b.y; a.z += b.z; a.w += b.w;
    }
    ((float4*)dst)[i] = a;
}

// ---------------- kernel R: rotary for q,k -> scratch (NO cache writes) --------
__global__ __launch_bounds__(128) void k_rot(const float* __restrict__ xqkv,
                                             const float* __restrict__ rot,
                                             float* __restrict__ qws,
                                             float* __restrict__ kws) {
    int c  = blockIdx.x;    // 0..39: 0-31 q heads, 32-39 k heads
    int b  = blockIdx.y;    // batch
    int dp = threadIdx.x;   // 0..127 output dim
    const float* row = &xqkv[(size_t)b * QKVC + c * HD];
    float acc = 0.f;
#pragma unroll 4
    for (int d = 0; d < HD; ++d) acc = fmaf(row[d], rot[d * HD + dp], acc);
    if (c < 32) {
        qws[((size_t)b * NH + c) * HD + dp] = acc;
    } else {
        int kvh = c - 32;
        kws[((size_t)b * NKV + kvh) * HD + dp] = acc;
    }
}

// ---------------- kernel B: flash attention, async-pipelined (T3/T4) -----------
// Round-5 structure (64-key tiles, 2 blocks/CU, counted vmcnt) + V prefetched
// TWO tiles ahead (triple reg buffer): steady-state outstanding 25 ops/wave
// ~50KB/CU in flight vs ~35KB Little's-law floor. Explicit 16-tile unroll
// (static buffer names, rule #20).
__global__ __launch_bounds__(256, 2) void k_attn(const float* __restrict__ ck,
                                                 const float* __restrict__ cv,
                                                 const float* __restrict__ qws,
                                                 const float* __restrict__ kws,
                                                 const float* __restrict__ xqkv,
                                                 const float* __restrict__ mask,
                                                 const int* __restrict__ curpos,
                                                 float* __restrict__ opart,
                                                 float2* __restrict__ stats) {
    __shared__ float Kl[2][64 * 128];   // 64 KB, linear (gll dest), XOR-swizzled
    __shared__ float mbuf[2][GQ * 64];  // 2 KB mask tiles
    __shared__ float ql[GQ][HD];        // 2 KB
    __shared__ float pl[GQ * 64];       // 1 KB
    __shared__ float rs[GQ];
    int bkv = blockIdx.x;               // 0..255
    int split = blockIdx.y;             // 0..3
    int b = bkv >> 3, kv = bkv & 7;
    int tid = threadIdx.x;
    int wv = tid >> 6, lane = tid & 63;    // phase A: wave = head
    int d4 = tid & 31, sub = tid >> 5;     // phase B: 8 subs x 8 keys
    int lrh = lane >> 5;                   // row half for staging
    int sbyte = (lane & 31) << 4;          // swizzle byte offset
    int pos = *curpos;
    int L = min((((pos + 1) + 31) >> 5) << 5, KVLEN);
    int l0 = split * 1024;
    int h = kv * GQ + wv;
    const float scale = 0.08838834764831845f;  // 1/sqrt(128)

    // q of own head -> LDS (wave-local)
    *(float2*)&ql[wv][lane * 2] = *(const float2*)&qws[((size_t)b * NH + h) * HD + lane * 2];

    // raw dot(q[h], k_new) for the `pos` row (broadcast loads, once per block)
    float posdot = 0.f;
    {
        const float4* kwr = (const float4*)&kws[((size_t)b * NKV + kv) * HD];
        const float4* qr  = (const float4*)&qws[((size_t)b * NH + h) * HD];
#pragma unroll
        for (int i = 0; i < 32; ++i) {
            float4 a = kwr[i], c = qr[i];
            posdot += a.x * c.x + a.y * c.y + a.z * c.z + a.w * c.w;
        }
    }
    float4 vnew4 = *(const float4*)&xqkv[(size_t)b * QKVC + (size_t)(NH + NKV) * HD + kv * HD + d4 * 4];

    const char*   Ktile0 = (const char*)(ck + ((size_t)bkv * KVLEN + l0) * HD);
    const float4* Vt0    = (const float4*)(cv + ((size_t)bkv * KVLEN + l0) * HD);

#define STAGE_K(T, BUFI) do {                                                    \
        const char* kb_ = Ktile0 + (size_t)(T) * 32768;                          \
        _Pragma("unroll")                                                        \
        for (int i_ = 0; i_ < 8; ++i_) {                                         \
            int row_ = (i_ * 4 + wv) * 2 + lrh;                                  \
            int col_ = sbyte ^ ((row_ & 31) << 4);                               \
            GLL16(kb_ + (size_t)row_ * 512 + col_, &Kl[BUFI][(i_ * 4 + wv) * 256]); \
        }                                                                        \
    } while (0)

#define STAGE_M(T, BUFI) do {                                                    \
        int hh_ = lane >> 4, kk_ = lane & 15;                                    \
        const float* mg_ = mask + (((size_t)(kv * GQ + hh_) * BB + b) * KVLEN    \
                                   + l0 + (T) * 64 + kk_ * 4);                   \
        GLL16(mg_, &mbuf[BUFI][0]);                                              \
    } while (0)

#define LOADV(T, VBUF) do {                                                      \
        _Pragma("unroll")                                                        \
        for (int i_ = 0; i_ < 8; ++i_)                                           \
            (VBUF)[i_] = Vt0[(size_t)((T) * 64 + sub * 8 + i_) * 32 + d4];       \
    } while (0)

    float m = -3.0e38f, lsum = 0.f;
    float4 acc[GQ];
#pragma unroll
    for (int gg = 0; gg < GQ; ++gg) acc[gg] = make_float4(0.f, 0.f, 0.f, 0.f);
    float4 vA[8], vB[8], vC[8];

    // prologue: K(0), M(0), V(0), V(1) in flight
    STAGE_K(0, 0);
    if (wv == 0) STAGE_M(0, 0);
    LOADV(0, vA);
    LOADV(1, vB);

#define TILE(T, KB, VCUR, VN2) do {                                              \
        if ((T) < 14) {                                                          \
            STAGE_K((T) + 1, (KB) ^ 1);                                          \
            if (wv == 0) STAGE_M((T) + 1, (KB) ^ 1);                             \
            LOADV((T) + 2, VN2);                                                 \
            if (wv == 0) asm volatile("s_waitcnt vmcnt(25)" ::: "memory");       \
            else         asm volatile("s_waitcnt vmcnt(24)" ::: "memory");       \
        } else if ((T) == 14) {                                                  \
            STAGE_K(15, (KB) ^ 1);                                               \
            if (wv == 0) STAGE_M(15, (KB) ^ 1);                                  \
            if (wv == 0) asm volatile("s_waitcnt vmcnt(17)" ::: "memory");       \
            else         asm volatile("s_waitcnt vmcnt(16)" ::: "memory");       \
        } else {                                                                 \
            asm volatile("s_waitcnt vmcnt(0)" ::: "memory");                     \
        }                                                                        \
        __builtin_amdgcn_s_barrier();                                            \
        /* phase A: pure LDS + VALU */                                           \
        int lk_ = l0 + (T) * 64 + lane;                                          \
        const char* klr_ = (const char*)&Kl[KB][0] + lane * 512;                 \
        float sdot_ = 0.f;                                                       \
        _Pragma("unroll")                                                        \
        for (int dd_ = 0; dd_ < 32; ++dd_) {                                     \
            float4 kk4_ = *(const float4*)(klr_ + ((dd_ * 16) ^ sbyte));         \
            float4 qq4_ = *(const float4*)&ql[wv][dd_ * 4];                      \
            sdot_ += kk4_.x * qq4_.x + kk4_.y * qq4_.y                           \
                   + kk4_.z * qq4_.z + kk4_.w * qq4_.w;                          \
        }                                                                        \
        if (lk_ == pos) sdot_ = posdot;                                          \
        float s_ = sdot_ * scale + mbuf[KB][wv * 64 + lane];                     \
        if (lk_ >= L) s_ = -3.0e38f;                                             \
        float smax_ = s_;                                                        \
        _Pragma("unroll")                                                        \
        for (int off_ = 32; off_ > 0; off_ >>= 1)                                \
            smax_ = fmaxf(smax_, __shfl_xor(smax_, off_));                       \
        float mnew_ = fmaxf(m, smax_);                                           \
        float r_ = __expf(m - mnew_);                                            \
        float e_ = (lk_ < L) ? __expf(s_ - mnew_) : 0.f;                         \
        float esum_ = e_;                                                        \
        _Pragma("unroll")                                                        \
        for (int off_ = 32; off_ > 0; off_ >>= 1)                                \
            esum_ += __shfl_xor(esum_, off_);                                    \
        lsum = lsum * r_ + esum_;                                                \
        m = mnew_;                                                               \
        pl[wv * 64 + lane] = e_;                                                 \
        if (lane == 0) rs[wv] = r_;                                              \
        asm volatile("s_waitcnt lgkmcnt(0)" ::: "memory");                       \
        __builtin_amdgcn_s_barrier();                                            \
        /* phase B: FMA from V regs, p via LDS broadcast */                      \
        int prow_ = pos - (l0 + (T) * 64);                                       \
        _Pragma("unroll")                                                        \
        for (int gg_ = 0; gg_ < GQ; ++gg_) {                                     \
            float rg_ = rs[gg_];                                                 \
            acc[gg_].x *= rg_; acc[gg_].y *= rg_;                                \
            acc[gg_].z *= rg_; acc[gg_].w *= rg_;                                \
        }                                                                        \
        _Pragma("unroll")                                                        \
        for (int i_ = 0; i_ < 8; ++i_) {                                         \
            float4 v_ = (sub * 8 + i_ == prow_) ? vnew4 : (VCUR)[i_];            \
            _Pragma("unroll")                                                    \
            for (int gg_ = 0; gg_ < GQ; ++gg_) {                                 \
                float p_ = pl[gg_ * 64 + sub * 8 + i_];                          \
                acc[gg_].x = fmaf(p_, v_.x, acc[gg_].x);                         \
                acc[gg_].y = fmaf(p_, v_.y, acc[gg_].y);                         \
                acc[gg_].z = fmaf(p_, v_.z, acc[gg_].z);                         \
                acc[gg_].w = fmaf(p_, v_.w, acc[gg_].w);                         \
            }                                                                    \
        }                                                                        \
    } while (0)

    // explicit 16-tile schedule: K LDS ping-pong (period 2), V regs (period 3)
    TILE(0,  0, vA, vC);  TILE(1,  1, vB, vA);  TILE(2,  0, vC, vB);
    TILE(3,  1, vA, vC);  TILE(4,  0, vB, vA);  TILE(5,  1, vC, vB);
    TILE(6,  0, vA, vC);  TILE(7,  1, vB, vA);  TILE(8,  0, vC, vB);
    TILE(9,  1, vA, vC);  TILE(10, 0, vB, vA);  TILE(11, 1, vC, vB);
    TILE(12, 0, vA, vC);  TILE(13, 1, vB, vA);  TILE(14, 0, vC, vA);
    TILE(15, 1, vA, vB);

    if (lane == 0) stats[(bkv * GQ + wv) * ASPLIT + split] = make_float2(m, lsum);

    // cross-sub reduce of O partials (alias Kl as scratch; pipeline done)
    __syncthreads();
    float* red = &Kl[0][0];   // 8*4*128 floats = 16 KB
#pragma unroll
    for (int gg = 0; gg < GQ; ++gg)
        *(float4*)&red[(sub * GQ + gg) * HD + d4 * 4] = acc[gg];
    __syncthreads();
#pragma unroll
    for (int rep = 0; rep < 2; ++rep) {
        int idx = rep * 256 + tid;         // 0..511 = (g,d)
        int g2 = idx >> 7, d = idx & 127;
        float o = 0.f;
#pragma unroll
        for (int k = 0; k < 8; ++k) o += red[(k * GQ + g2) * HD + d];
        opart[(((size_t)split * 256 + bkv) * GQ + g2) * HD + d] = o;
    }
#undef TILE
#undef LOADV
#undef STAGE_K
#undef STAGE_M
}

// ---------------- kernel M: merge ASPLIT split partials -> attn ----------------
__global__ __launch_bounds__(128) void k_merge(const float* __restrict__ opart,
                                               const float2* __restrict__ stats,
                                               float* __restrict__ attn) {
    int bkv = blockIdx.x;    // 0..255
    int d = threadIdx.x;     // 0..127
    int b = bkv >> 3, kv = bkv & 7;
#pragma unroll
    for (int g = 0; g < GQ; ++g) {
        float2 st[ASPLIT];
        float M = -3.0e38f;
#pragma unroll
        for (int s = 0; s < ASPLIT; ++s) {
            st[s] = stats[(bkv * GQ + g) * ASPLIT + s];
            M = fmaxf(M, st[s].x);
        }
        float Ltot = 0.f;
        float w[ASPLIT];
#pragma unroll
        for (int s = 0; s < ASPLIT; ++s) {
            w[s] = __expf(st[s].x - M);
            Ltot += st[s].y * w[s];
        }
        float inv = Ltot > 0.f ? 1.f / Ltot : 0.f;
        float o = 0.f;
#pragma unroll
        for (int s = 0; s < ASPLIT; ++s)
            o += opart[(((size_t)s * 256 + bkv) * GQ + g) * HD + d] * (w[s] * inv);
        attn[(size_t)b * DIM + (kv * GQ + g) * HD + d] = o;
    }
}

// ---------------- kernel C: out partials = attn @ wo (K-split, partials) -------
__global__ __launch_bounds__(256, 4) void k_wo(const float* __restrict__ attn,
                                               const float* __restrict__ wo,
                                               float* __restrict__ part) {
    int j  = blockIdx.x * 256 + threadIdx.x;       // 0..4095 (16 blocks)
    int d0 = blockIdx.y * (DIM / WO_SPLITS);       // 128 rows per split
    float acc[BB];
#pragma unroll
    for (int b = 0; b < BB; ++b) acc[b] = 0.f;
    for (int dd = d0; dd < d0 + DIM / WO_SPLITS; dd += 8) {
        float wr[8];
#pragma unroll
        for (int k = 0; k < 8; ++k) wr[k] = wo[(size_t)(dd + k) * DIM + j];
#pragma unroll
        for (int b = 0; b < BB; ++b) {
            float4 xa = *(const float4*)&attn[b * DIM + dd];   // wave-uniform
            float4 xb = *(const float4*)&attn[b * DIM + dd + 4];
            float t = acc[b];
            t = fmaf(xa.x, wr[0], t); t = fmaf(xa.y, wr[1], t);
            t = fmaf(xa.z, wr[2], t); t = fmaf(xa.w, wr[3], t);
            t = fmaf(xb.x, wr[4], t); t = fmaf(xb.y, wr[5], t);
            t = fmaf(xb.z, wr[6], t); t = fmaf(xb.w, wr[7], t);
            acc[b] = t;
        }
    }
#pragma unroll
    for (int b = 0; b < BB; ++b)
        part[(size_t)blockIdx.y * (BB * DIM) + (size_t)b * DIM + j] = acc[b];
}

extern "C" void kernel_launch(void* const* d_in, const int* in_sizes, int n_in,
                              void* d_out, int out_size, void* d_ws, size_t ws_size,
                              hipStream_t stream) {
    const float* x    = (const float*)d_in[0];
    const float* wqkv = (const float*)d_in[1];
    const float* wo   = (const float*)d_in[2];
    const float* rot  = (const float*)d_in[3];
    const float* ck   = (const float*)d_in[4];   // read-only (no cache mutation)
    const float* cv   = (const float*)d_in[5];
    const float* mask = (const float*)d_in[6];
    const int* curpos = (const int*)d_in[7];
    float* out        = (float*)d_out;

    char* ws = (char*)d_ws;
    float*  xqkv_part = (float*)(ws);                   // 25,165,824
    float*  xqkv      = (float*)(ws + 25165824);        // 786,432
    float*  qws       = (float*)(ws + 25952256);        // 524,288
    float*  kws       = (float*)(ws + 26476544);        // 131,072
    float*  opart     = (float*)(ws + 26607616);        // 4*256*4*128*4 = 2,097,152
    float2* stats     = (float2*)(ws + 28704768);       // 1024*4*8 = 32,768
    float*  attn      = (float*)(ws + 28737536);        // 524,288
    float*  out_part  = (float*)(ws + 29261824);        // 16,777,216
    // total ws used ~46 MB

    k_qkv  <<<dim3(QKVC / 256, QKV_SPLITS), 256, 0, stream>>>(x, wqkv, xqkv_part);
    k_red  <<<dim3(192),                    256, 0, stream>>>(xqkv_part, xqkv, QKV_SPLITS, BB * QKVC / 4);
    k_rot  <<<dim3(40, BB),                 128, 0, stream>>>(xqkv, rot, qws, kws);
    k_attn <<<dim3(BB * NKV, ASPLIT),       256, 0, stream>>>(ck, cv, qws, kws, xqkv, mask, curpos, opart, stats);
    k_merge<<<dim3(BB * NKV),               128, 0, stream>>>(opart, stats, attn);
    k_wo   <<<dim3(DIM / 256, WO_SPLITS),   256, 0, stream>>>(attn, wo, out_part);
    k_red  <<<dim3(128),                    256, 0, stream>>>(out_part, out, WO_SPLITS, BB * DIM / 4);
}

// Round 8
// 1318.215 us; speedup vs baseline: 1.3862x; 1.3862x over previous
//
#include <hip/hip_runtime.h>

#define BB 32
#define DIM 4096
#define NH 32
#define NKV 8
#define HD 128
#define KVLEN 4096
#define QKVC 6144  // DIM + 2*NKV*HD
#define GQ 4
#define QKV_SPLITS 32
#define WO_SPLITS 32
#define ASPLIT 2   // KV splits for k_attn (2048 keys each) -> 512 blocks, ALL resident
#define NT 32      // tiles per block (2048 / 64)

typedef const __attribute__((address_space(1))) char gas_char;
typedef __attribute__((address_space(3))) char las_char;
#define GLL16(GP, LP) __builtin_amdgcn_global_load_lds((gas_char*)(GP), (las_char*)(LP), 16, 0, 0)

// ---------------- kernel A: xqkv partials = x @ wqkv (K-split, partials) -------
// 16-deep weight pipeline: 16x256B per wave in flight (~60 VGPR, no spill).
__global__ __launch_bounds__(256, 4) void k_qkv(const float* __restrict__ x,
                                                const float* __restrict__ w,
                                                float* __restrict__ part) {
    int j  = blockIdx.x * 256 + threadIdx.x;          // column 0..6143 (24 blocks)
    int d0 = blockIdx.y * (DIM / QKV_SPLITS);         // 128 rows per split
    float acc[BB];
#pragma unroll
    for (int b = 0; b < BB; ++b) acc[b] = 0.f;
    for (int dd = d0; dd < d0 + DIM / QKV_SPLITS; dd += 16) {
        float wr[16];
#pragma unroll
        for (int k = 0; k < 16; ++k) wr[k] = w[(size_t)(dd + k) * QKVC + j];
#pragma unroll
        for (int b = 0; b < BB; ++b) {
            float4 xa = *(const float4*)&x[b * DIM + dd];      // wave-uniform
            float4 xb = *(const float4*)&x[b * DIM + dd + 4];
            float4 xc = *(const float4*)&x[b * DIM + dd + 8];
            float4 xd = *(const float4*)&x[b * DIM + dd + 12];
            float t = acc[b];
            t = fmaf(xa.x, wr[0],  t); t = fmaf(xa.y, wr[1],  t);
            t = fmaf(xa.z, wr[2],  t); t = fmaf(xa.w, wr[3],  t);
            t = fmaf(xb.x, wr[4],  t); t = fmaf(xb.y, wr[5],  t);
            t = fmaf(xb.z, wr[6],  t); t = fmaf(xb.w, wr[7],  t);
            t = fmaf(xc.x, wr[8],  t); t = fmaf(xc.y, wr[9],  t);
            t = fmaf(xc.z, wr[10], t); t = fmaf(xc.w, wr[11], t);
            t = fmaf(xd.x, wr[12], t); t = fmaf(xd.y, wr[13], t);
            t = fmaf(xd.z, wr[14], t); t = fmaf(xd.w, wr[15], t);
            acc[b] = t;
        }
    }
#pragma unroll
    for (int b = 0; b < BB; ++b)
        part[(size_t)blockIdx.y * (BB * QKVC) + (size_t)b * QKVC + j] = acc[b];
}

// ---------------- generic split reduction: dst = sum_p src[p] ------------------
__global__ __launch_bounds__(256) void k_red(const float* __restrict__ src,
                                             float* __restrict__ dst,
                                             int parts, int n4) {
    int i = blockIdx.x * 256 + threadIdx.x;
    if (i >= n4) return;
    const float4* s4 = (const float4*)src;
    float4 a = s4[i];
    for (int p = 1; p < parts; ++p) {
        float4 b = s4[(size_t)p * n4 + i];
        a.x += b.x; a.y += b.y; a.z += b.z; a.w += b.w;
    }
    ((float4*)dst)[i] = a;
}

// ---------------- kernel R: rotary for q,k -> scratch (NO cache writes) --------
__global__ __launch_bounds__(128) void k_rot(const float* __restrict__ xqkv,
                                             const float* __restrict__ rot,
                                             float* __restrict__ qws,
                                             float* __restrict__ kws) {
    int c  = blockIdx.x;    // 0..39: 0-31 q heads, 32-39 k heads
    int b  = blockIdx.y;    // batch
    int dp = threadIdx.x;   // 0..127 output dim
    const float* row = &xqkv[(size_t)b * QKVC + c * HD];
    float acc = 0.f;
#pragma unroll 4
    for (int d = 0; d < HD; ++d) acc = fmaf(row[d], rot[d * HD + dp], acc);
    if (c < 32) {
        qws[((size_t)b * NH + c) * HD + dp] = acc;
    } else {
        int kvh = c - 32;
        kws[((size_t)b * NKV + kvh) * HD + dp] = acc;
    }
}

// ---------------- kernel B: flash attention, async-pipelined (T3/T4) -----------
// Round-5 proven schedule: 64-key tiles, GLL K staging (XOR-swizzled source),
// V double-buffered in regs (2-deep ONLY - 3-deep spills, round-7 lesson),
// counted vmcnt 17/16, raw s_barrier. Delta vs r5: ASPLIT=2 -> 512 blocks all
// co-resident (one occupancy round; no mid-kernel pipeline fill/drain).
__global__ __launch_bounds__(256, 2) void k_attn(const float* __restrict__ ck,
                                                 const float* __restrict__ cv,
                                                 const float* __restrict__ qws,
                                                 const float* __restrict__ kws,
                                                 const float* __restrict__ xqkv,
                                                 const float* __restrict__ mask,
                                                 const int* __restrict__ curpos,
                                                 float* __restrict__ opart,
                                                 float2* __restrict__ stats) {
    __shared__ float Kl[2][64 * 128];   // 64 KB, linear (gll dest), XOR-swizzled
    __shared__ float mbuf[2][GQ * 64];  // 2 KB mask tiles
    __shared__ float ql[GQ][HD];        // 2 KB
    __shared__ float pl[GQ * 64];       // 1 KB
    __shared__ float rs[GQ];
    int bkv = blockIdx.x;               // 0..255
    int split = blockIdx.y;             // 0..1
    int b = bkv >> 3, kv = bkv & 7;
    int tid = threadIdx.x;
    int wv = tid >> 6, lane = tid & 63;    // phase A: wave = head
    int d4 = tid & 31, sub = tid >> 5;     // phase B: 8 subs x 8 keys
    int lrh = lane >> 5;                   // row half for staging
    int sbyte = (lane & 31) << 4;          // swizzle byte offset
    int pos = *curpos;
    int L = min((((pos + 1) + 31) >> 5) << 5, KVLEN);
    int l0 = split * (NT * 64);
    int h = kv * GQ + wv;
    const float scale = 0.08838834764831845f;  // 1/sqrt(128)

    // q of own head -> LDS (wave-local)
    *(float2*)&ql[wv][lane * 2] = *(const float2*)&qws[((size_t)b * NH + h) * HD + lane * 2];

    // raw dot(q[h], k_new) for the `pos` row (broadcast loads, once per block)
    float posdot = 0.f;
    {
        const float4* kwr = (const float4*)&kws[((size_t)b * NKV + kv) * HD];
        const float4* qr  = (const float4*)&qws[((size_t)b * NH + h) * HD];
#pragma unroll
        for (int i = 0; i < 32; ++i) {
            float4 a = kwr[i], c = qr[i];
            posdot += a.x * c.x + a.y * c.y + a.z * c.z + a.w * c.w;
        }
    }
    float4 vnew4 = *(const float4*)&xqkv[(size_t)b * QKVC + (size_t)(NH + NKV) * HD + kv * HD + d4 * 4];

    const char*   Ktile0 = (const char*)(ck + ((size_t)bkv * KVLEN + l0) * HD);
    const float4* Vt0    = (const float4*)(cv + ((size_t)bkv * KVLEN + l0) * HD);

#define STAGE_K(T, BUFI) do {                                                    \
        const char* kb_ = Ktile0 + (size_t)(T) * 32768;                          \
        _Pragma("unroll")                                                        \
        for (int i_ = 0; i_ < 8; ++i_) {                                         \
            int row_ = (i_ * 4 + wv) * 2 + lrh;                                  \
            int col_ = sbyte ^ ((row_ & 31) << 4);                               \
            GLL16(kb_ + (size_t)row_ * 512 + col_, &Kl[BUFI][(i_ * 4 + wv) * 256]); \
        }                                                                        \
    } while (0)

#define STAGE_M(T, BUFI) do {                                                    \
        int hh_ = lane >> 4, kk_ = lane & 15;                                    \
        const float* mg_ = mask + (((size_t)(kv * GQ + hh_) * BB + b) * KVLEN    \
                                   + l0 + (T) * 64 + kk_ * 4);                   \
        GLL16(mg_, &mbuf[BUFI][0]);                                              \
    } while (0)

    float m = -3.0e38f, lsum = 0.f;
    float4 acc[GQ];
#pragma unroll
    for (int gg = 0; gg < GQ; ++gg) acc[gg] = make_float4(0.f, 0.f, 0.f, 0.f);
    float4 vA[8], vB[8];

    // prologue: tile 0 in flight
    STAGE_K(0, 0);
    if (wv == 0) STAGE_M(0, 0);
#pragma unroll
    for (int i = 0; i < 8; ++i) vA[i] = Vt0[(size_t)(sub * 8 + i) * 32 + d4];

#define TILE(T, BUFI, VC, VN) do {                                               \
        if ((T) < NT - 1) {                                                      \
            STAGE_K((T) + 1, (BUFI) ^ 1);                                        \
            if (wv == 0) STAGE_M((T) + 1, (BUFI) ^ 1);                           \
            _Pragma("unroll")                                                    \
            for (int i_ = 0; i_ < 8; ++i_)                                       \
                (VN)[i_] = Vt0[(size_t)(((T) + 1) * 64 + sub * 8 + i_) * 32 + d4]; \
            if (wv == 0) asm volatile("s_waitcnt vmcnt(17)" ::: "memory");       \
            else         asm volatile("s_waitcnt vmcnt(16)" ::: "memory");       \
        } else {                                                                 \
            asm volatile("s_waitcnt vmcnt(0)" ::: "memory");                     \
        }                                                                        \
        __builtin_amdgcn_s_barrier();                                            \
        /* phase A: pure LDS + VALU */                                           \
        int lk_ = l0 + (T) * 64 + lane;                                          \
        const char* klr_ = (const char*)&Kl[BUFI][0] + lane * 512;               \
        float sdot_ = 0.f;                                                       \
        _Pragma("unroll")                                                        \
        for (int dd_ = 0; dd_ < 32; ++dd_) {                                     \
            float4 kk4_ = *(const float4*)(klr_ + ((dd_ * 16) ^ sbyte));         \
            float4 qq4_ = *(const float4*)&ql[wv][dd_ * 4];                      \
            sdot_ += kk4_.x * qq4_.x + kk4_.y * qq4_.y                           \
                   + kk4_.z * qq4_.z + kk4_.w * qq4_.w;                          \
        }                                                                        \
        if (lk_ == pos) sdot_ = posdot;                                          \
        float s_ = sdot_ * scale + mbuf[BUFI][wv * 64 + lane];                   \
        if (lk_ >= L) s_ = -3.0e38f;                                             \
        float smax_ = s_;                                                        \
        _Pragma("unroll")                                                        \
        for (int off_ = 32; off_ > 0; off_ >>= 1)                                \
            smax_ = fmaxf(smax_, __shfl_xor(smax_, off_));                       \
        float mnew_ = fmaxf(m, smax_);                                           \
        float r_ = __expf(m - mnew_);                                            \
        float e_ = (lk_ < L) ? __expf(s_ - mnew_) : 0.f;                         \
        float esum_ = e_;                                                        \
        _Pragma("unroll")                                                        \
        for (int off_ = 32; off_ > 0; off_ >>= 1)                                \
            esum_ += __shfl_xor(esum_, off_);                                    \
        lsum = lsum * r_ + esum_;                                                \
        m = mnew_;                                                               \
        pl[wv * 64 + lane] = e_;                                                 \
        if (lane == 0) rs[wv] = r_;                                              \
        asm volatile("s_waitcnt lgkmcnt(0)" ::: "memory");                       \
        __builtin_amdgcn_s_barrier();                                            \
        /* phase B: FMA from V regs, p via LDS broadcast */                      \
        int prow_ = pos - (l0 + (T) * 64);                                       \
        _Pragma("unroll")                                                        \
        for (int gg_ = 0; gg_ < GQ; ++gg_) {                                     \
            float rg_ = rs[gg_];                                                 \
            acc[gg_].x *= rg_; acc[gg_].y *= rg_;                                \
            acc[gg_].z *= rg_; acc[gg_].w *= rg_;                                \
        }                                                                        \
        _Pragma("unroll")                                                        \
        for (int i_ = 0; i_ < 8; ++i_) {                                         \
            float4 v_ = (sub * 8 + i_ == prow_) ? vnew4 : (VC)[i_];              \
            _Pragma("unroll")                                                    \
            for (int gg_ = 0; gg_ < GQ; ++gg_) {                                 \
                float p_ = pl[gg_ * 64 + sub * 8 + i_];                          \
                acc[gg_].x = fmaf(p_, v_.x, acc[gg_].x);                         \
                acc[gg_].y = fmaf(p_, v_.y, acc[gg_].y);                         \
                acc[gg_].z = fmaf(p_, v_.z, acc[gg_].z);                         \
                acc[gg_].w = fmaf(p_, v_.w, acc[gg_].w);                         \
            }                                                                    \
        }                                                                        \
    } while (0)

    for (int tt = 0; tt < NT; tt += 2) {
        TILE(tt,     0, vA, vB);
        TILE(tt + 1, 1, vB, vA);
    }

    if (lane == 0) stats[(bkv * GQ + wv) * ASPLIT + split] = make_float2(m, lsum);

    // cross-sub reduce of O partials (alias Kl as scratch; pipeline done)
    __syncthreads();
    float* red = &Kl[0][0];   // 8*4*128 floats = 16 KB
#pragma unroll
    for (int gg = 0; gg < GQ; ++gg)
        *(float4*)&red[(sub * GQ + gg) * HD + d4 * 4] = acc[gg];
    __syncthreads();
#pragma unroll
    for (int rep = 0; rep < 2; ++rep) {
        int idx = rep * 256 + tid;         // 0..511 = (g,d)
        int g2 = idx >> 7, d = idx & 127;
        float o = 0.f;
#pragma unroll
        for (int k = 0; k < 8; ++k) o += red[(k * GQ + g2) * HD + d];
        opart[(((size_t)split * 256 + bkv) * GQ + g2) * HD + d] = o;
    }
#undef TILE
#undef STAGE_K
#undef STAGE_M
}

// ---------------- kernel M: merge ASPLIT split partials -> attn ----------------
__global__ __launch_bounds__(128) void k_merge(const float* __restrict__ opart,
                                               const float2* __restrict__ stats,
                                               float* __restrict__ attn) {
    int bkv = blockIdx.x;    // 0..255
    int d = threadIdx.x;     // 0..127
    int b = bkv >> 3, kv = bkv & 7;
#pragma unroll
    for (int g = 0; g < GQ; ++g) {
        float2 st[ASPLIT];
        float M = -3.0e38f;
#pragma unroll
        for (int s = 0; s < ASPLIT; ++s) {
            st[s] = stats[(bkv * GQ + g) * ASPLIT + s];
            M = fmaxf(M, st[s].x);
        }
        float Ltot = 0.f;
        float w[ASPLIT];
#pragma unroll
        for (int s = 0; s < ASPLIT; ++s) {
            w[s] = __expf(st[s].x - M);
            Ltot += st[s].y * w[s];
        }
        float inv = Ltot > 0.f ? 1.f / Ltot : 0.f;
        float o = 0.f;
#pragma unroll
        for (int s = 0; s < ASPLIT; ++s)
            o += opart[(((size_t)s * 256 + bkv) * GQ + g) * HD + d] * (w[s] * inv);
        attn[(size_t)b * DIM + (kv * GQ + g) * HD + d] = o;
    }
}

// ---------------- kernel C: out partials = attn @ wo (K-split, partials) -------
__global__ __launch_bounds__(256, 4) void k_wo(const float* __restrict__ attn,
                                               const float* __restrict__ wo,
                                               float* __restrict__ part) {
    int j  = blockIdx.x * 256 + threadIdx.x;       // 0..4095 (16 blocks)
    int d0 = blockIdx.y * (DIM / WO_SPLITS);       // 128 rows per split
    float acc[BB];
#pragma unroll
    for (int b = 0; b < BB; ++b) acc[b] = 0.f;
    for (int dd = d0; dd < d0 + DIM / WO_SPLITS; dd += 8) {
        float wr[8];
#pragma unroll
        for (int k = 0; k < 8; ++k) wr[k] = wo[(size_t)(dd + k) * DIM + j];
#pragma unroll
        for (int b = 0; b < BB; ++b) {
            float4 xa = *(const float4*)&attn[b * DIM + dd];   // wave-uniform
            float4 xb = *(const float4*)&attn[b * DIM + dd + 4];
            float t = acc[b];
            t = fmaf(xa.x, wr[0], t); t = fmaf(xa.y, wr[1], t);
            t = fmaf(xa.z, wr[2], t); t = fmaf(xa.w, wr[3], t);
            t = fmaf(xb.x, wr[4], t); t = fmaf(xb.y, wr[5], t);
            t = fmaf(xb.z, wr[6], t); t = fmaf(xb.w, wr[7], t);
            acc[b] = t;
        }
    }
#pragma unroll
    for (int b = 0; b < BB; ++b)
        part[(size_t)blockIdx.y * (BB * DIM) + (size_t)b * DIM + j] = acc[b];
}

extern "C" void kernel_launch(void* const* d_in, const int* in_sizes, int n_in,
                              void* d_out, int out_size, void* d_ws, size_t ws_size,
                              hipStream_t stream) {
    const float* x    = (const float*)d_in[0];
    const float* wqkv = (const float*)d_in[1];
    const float* wo   = (const float*)d_in[2];
    const float* rot  = (const float*)d_in[3];
    const float* ck   = (const float*)d_in[4];   // read-only (no cache mutation)
    const float* cv   = (const float*)d_in[5];
    const float* mask = (const float*)d_in[6];
    const int* curpos = (const int*)d_in[7];
    float* out        = (float*)d_out;

    char* ws = (char*)d_ws;
    float*  xqkv_part = (float*)(ws);                   // 25,165,824
    float*  xqkv      = (float*)(ws + 25165824);        // 786,432
    float*  qws       = (float*)(ws + 25952256);        // 524,288
    float*  kws       = (float*)(ws + 26476544);        // 131,072
    float*  opart     = (float*)(ws + 26607616);        // 2*256*4*128*4 = 1,048,576
    float2* stats     = (float2*)(ws + 28704768);       // 1024*2*8 = 16,384
    float*  attn      = (float*)(ws + 28737536);        // 524,288
    float*  out_part  = (float*)(ws + 29261824);        // 16,777,216
    // total ws used ~46 MB

    k_qkv  <<<dim3(QKVC / 256, QKV_SPLITS), 256, 0, stream>>>(x, wqkv, xqkv_part);
    k_red  <<<dim3(192),                    256, 0, stream>>>(xqkv_part, xqkv, QKV_SPLITS, BB * QKVC / 4);
    k_rot  <<<dim3(40, BB),                 128, 0, stream>>>(xqkv, rot, qws, kws);
    k_attn <<<dim3(BB * NKV, ASPLIT),       256, 0, stream>>>(ck, cv, qws, kws, xqkv, mask, curpos, opart, stats);
    k_merge<<<dim3(BB * NKV),               128, 0, stream>>>(opart, stats, attn);
    k_wo   <<<dim3(DIM / 256, WO_SPLITS),   256, 0, stream>>>(attn, wo, out_part);
    k_red  <<<dim3(128),                    256, 0, stream>>>(out_part, out, WO_SPLITS, BB * DIM / 4);
}